// Round 5
// baseline (885.977 us; speedup 1.0000x reference)
//
#include <hip/hip_runtime.h>
#include <math.h>

#define F0 512
#define F1 16
#define F2 40
#define RPC 256         // rows per coarse bucket
#define RPC_SHIFT 8
#define COL_BITS 17     // n <= 131072; local row (8b) in bits 17..24
#define EPB 8192        // edges per partition block
#define MAXNBC 512

// ---------------- phase 1: per-block LDS histogram over coarse buckets --------
__global__ __launch_bounds__(256) void k_part_hist(const int* __restrict__ row, int E,
                                                   int B1, int NBC,
                                                   int* __restrict__ bh) {
    __shared__ int lh[MAXNBC];
    int t = threadIdx.x, blk = blockIdx.x;
    for (int i = t; i < NBC; i += 256) lh[i] = 0;
    __syncthreads();
    int base0 = blk * EPB;
#pragma unroll
    for (int q = 0; q < EPB / 1024; q++) {
        int base = base0 + q * 1024 + t * 4;
        if (base + 3 < E) {
            int4 r = *(const int4*)(row + base);
            atomicAdd(&lh[r.x >> RPC_SHIFT], 1);
            atomicAdd(&lh[r.y >> RPC_SHIFT], 1);
            atomicAdd(&lh[r.z >> RPC_SHIFT], 1);
            atomicAdd(&lh[r.w >> RPC_SHIFT], 1);
        } else {
            for (int e = base; e < E && e < base + 4; e++)
                atomicAdd(&lh[row[e] >> RPC_SHIFT], 1);
        }
    }
    __syncthreads();
    for (int i = t; i < NBC; i += 256) bh[i * B1 + blk] = lh[i];  // bin-major
}

// ---------------- phase 2: scan of NBC*B1 counts (bin-major order) ------------
__global__ __launch_bounds__(1024) void k_part_scan(int* __restrict__ bh, int NEL,
                                                    int B1, int* __restrict__ cbstart) {
    __shared__ int part[1024];
    int t = threadIdx.x;
    int Q = (NEL + 1023) >> 10;
    int i0 = t * Q;
    int s = 0;
    for (int q = 0; q < Q; q++) {
        int idx = i0 + q;
        if (idx < NEL) s += bh[idx];
    }
    part[t] = s;
    __syncthreads();
    for (int off = 1; off < 1024; off <<= 1) {
        int a = (t >= off) ? part[t - off] : 0;
        __syncthreads();
        part[t] += a;
        __syncthreads();
    }
    int run = (t > 0) ? part[t - 1] : 0;
    for (int q = 0; q < Q; q++) {
        int idx = i0 + q;
        if (idx < NEL) {
            int v = bh[idx];
            bh[idx] = run;  // in-place exclusive prefix
            if (idx % B1 == 0) cbstart[idx / B1] = run;
            run += v;
        }
    }
}

// ---------------- phase 3: fill — LDS cursors, zero global atomics ------------
__global__ __launch_bounds__(256) void k_part_fill(const int* __restrict__ row,
                                                   const int* __restrict__ col, int E,
                                                   int B1, int NBC,
                                                   const int* __restrict__ bh,
                                                   int* __restrict__ ebuf) {
    __shared__ int lcur[MAXNBC];
    int t = threadIdx.x, blk = blockIdx.x;
    for (int i = t; i < NBC; i += 256) lcur[i] = bh[i * B1 + blk];
    __syncthreads();
    int base0 = blk * EPB;
#pragma unroll
    for (int q = 0; q < EPB / 1024; q++) {
        int base = base0 + q * 1024 + t * 4;
        if (base + 3 < E) {
            int4 r = *(const int4*)(row + base);
            int4 c = *(const int4*)(col + base);
            int p;
            p = atomicAdd(&lcur[r.x >> RPC_SHIFT], 1);
            ebuf[p] = ((r.x & (RPC - 1)) << COL_BITS) | c.x;
            p = atomicAdd(&lcur[r.y >> RPC_SHIFT], 1);
            ebuf[p] = ((r.y & (RPC - 1)) << COL_BITS) | c.y;
            p = atomicAdd(&lcur[r.z >> RPC_SHIFT], 1);
            ebuf[p] = ((r.z & (RPC - 1)) << COL_BITS) | c.z;
            p = atomicAdd(&lcur[r.w >> RPC_SHIFT], 1);
            ebuf[p] = ((r.w & (RPC - 1)) << COL_BITS) | c.w;
        } else {
            for (int e = base; e < E && e < base + 4; e++) {
                int r = row[e], c = col[e];
                int p = atomicAdd(&lcur[r >> RPC_SHIFT], 1);
                ebuf[p] = ((r & (RPC - 1)) << COL_BITS) | c;
            }
        }
    }
}

// ---------------- phase 4: per-bucket counting sort (256 rows) ---------------
__global__ __launch_bounds__(256) void k_bsort(const int* __restrict__ ebuf,
                                               const int* __restrict__ cbstart, int NBC,
                                               int E, int n, int* __restrict__ colsort,
                                               int* __restrict__ deg,
                                               int* __restrict__ rs,
                                               float* __restrict__ dinv) {
    __shared__ int cnt[RPC];
    __shared__ int pre[RPC];
    int b = blockIdx.x, t = threadIdx.x;
    int r0 = b << RPC_SHIFT;
    int start = cbstart[b];
    int end = (b + 1 < NBC) ? cbstart[b + 1] : E;
    cnt[t] = 0;
    __syncthreads();
    for (int e = start + t; e < end; e += 256)
        atomicAdd(&cnt[ebuf[e] >> COL_BITS], 1);
    __syncthreads();
    int v = cnt[t];
    pre[t] = v;
    __syncthreads();
    for (int off = 1; off < 256; off <<= 1) {
        int a = (t >= off) ? pre[t - off] : 0;
        __syncthreads();
        pre[t] += a;
        __syncthreads();
    }
    int excl = pre[t] - v;
    int i = r0 + t;
    if (i < n) {
        deg[i] = v;
        rs[i] = start + excl;
        dinv[i] = rsqrtf((float)(v + 1));
    }
    __syncthreads();
    cnt[t] = excl;  // reuse as cursor
    __syncthreads();
    for (int e = start + t; e < end; e += 256) {
        int pv = ebuf[e];
        int lr = pv >> COL_BITS;
        int p = atomicAdd(&cnt[lr], 1);
        colsort[start + p] = pv & ((1 << COL_BITS) - 1);
    }
}

// ---------------- GEMM1: hp[i][j] = dinv[i] * (x[i,:] @ W1[:,j]) ----------------
__global__ __launch_bounds__(256) void k_gemm1(const float* __restrict__ x,
                                               const float* __restrict__ W1,
                                               const float* __restrict__ dinv,
                                               float* __restrict__ hp, int n,
                                               int total_waves) {
    int lane = threadIdx.x & 63;
    int wid = blockIdx.x * (blockDim.x >> 6) + (threadIdx.x >> 6);

    float w[8][16];
#pragma unroll
    for (int h = 0; h < 2; h++) {
#pragma unroll
        for (int r = 0; r < 4; r++) {
            int k = h * 256 + 4 * lane + r;
            const float4* p = (const float4*)(W1 + k * 16);
            float4 a = p[0], b = p[1], c = p[2], d = p[3];
            float* wr = w[h * 4 + r];
            wr[0] = a.x; wr[1] = a.y; wr[2] = a.z; wr[3] = a.w;
            wr[4] = b.x; wr[5] = b.y; wr[6] = b.z; wr[7] = b.w;
            wr[8] = c.x; wr[9] = c.y; wr[10] = c.z; wr[11] = c.w;
            wr[12] = d.x; wr[13] = d.y; wr[14] = d.z; wr[15] = d.w;
        }
    }

    for (int i = wid; i < n; i += total_waves) {
        const float4* xp = (const float4*)(x + (size_t)i * F0);
        float4 xa = xp[lane];
        float4 xb = xp[64 + lane];
        float acc[16];
#pragma unroll
        for (int j = 0; j < 16; j++) {
            acc[j] = xa.x * w[0][j] + xa.y * w[1][j] + xa.z * w[2][j] + xa.w * w[3][j]
                   + xb.x * w[4][j] + xb.y * w[5][j] + xb.z * w[6][j] + xb.w * w[7][j];
        }
#pragma unroll
        for (int j = 0; j < 16; j++) {
            float v = acc[j];
            v += __shfl_xor(v, 1);
            v += __shfl_xor(v, 2);
            v += __shfl_xor(v, 4);
            v += __shfl_xor(v, 8);
            v += __shfl_xor(v, 16);
            v += __shfl_xor(v, 32);
            acc[j] = v;
        }
        if (lane < 16) {
            float v = acc[0];
#pragma unroll
            for (int j = 1; j < 16; j++) v = (lane == j) ? acc[j] : v;
            hp[(size_t)i * F1 + lane] = dinv[i] * v;
        }
    }
}

// ---------------- SpMM1 + relu, store s2 = dinv * h1 (16 feats) ----------------
__global__ __launch_bounds__(256) void k_spmm1(const float* __restrict__ hp,
                                               const int* __restrict__ rs,
                                               const int* __restrict__ deg,
                                               const int* __restrict__ colsort,
                                               const float* __restrict__ dinv,
                                               const float* __restrict__ b1,
                                               float* __restrict__ s2, int n) {
    int t = threadIdx.x;
    int lane = t & 63;
    int g = lane >> 4;
    int jf = lane & 15;
    int i = blockIdx.x * 4 + (t >> 6);
    if (i >= n) return;
    int s = rs[i], c = deg[i];
    float acc = (g == 0) ? hp[(size_t)i * F1 + jf] : 0.f;
    int e = g;
    for (; e + 4 < c; e += 8) {
        int c0 = colsort[s + e];
        int c1 = colsort[s + e + 4];
        float v0 = hp[(size_t)c0 * F1 + jf];
        float v1 = hp[(size_t)c1 * F1 + jf];
        acc += v0 + v1;
    }
    if (e < c) acc += hp[(size_t)colsort[s + e] * F1 + jf];
    acc += __shfl_xor(acc, 16);
    acc += __shfl_xor(acc, 32);
    float di = dinv[i];
    float h1 = fmaxf(di * acc + b1[jf], 0.f);
    if (lane < 16) s2[(size_t)i * F1 + jf] = di * h1;
}

// ---------------- SpMM2 (16 feats) + GEMM2 + bias + log_softmax ----------------
__global__ __launch_bounds__(256) void k_spmm2(const float* __restrict__ s2,
                                               const int* __restrict__ rs,
                                               const int* __restrict__ deg,
                                               const int* __restrict__ colsort,
                                               const float* __restrict__ dinv,
                                               const float* __restrict__ W2,
                                               const float* __restrict__ b2,
                                               float* __restrict__ out, int n) {
    __shared__ float sW2[F1 * F2];
    int t = threadIdx.x;
    for (int idx = t; idx < F1 * F2; idx += 256) sW2[idx] = W2[idx];
    __syncthreads();

    int lane = t & 63;
    int g = lane >> 4;
    int jf = lane & 15;
    int i = blockIdx.x * 4 + (t >> 6);
    if (i >= n) return;
    int s = rs[i], c = deg[i];
    float acc = (g == 0) ? s2[(size_t)i * F1 + jf] : 0.f;
    int e = g;
    for (; e + 4 < c; e += 8) {
        int c0 = colsort[s + e];
        int c1 = colsort[s + e + 4];
        float v0 = s2[(size_t)c0 * F1 + jf];
        float v1 = s2[(size_t)c1 * F1 + jf];
        acc += v0 + v1;
    }
    if (e < c) acc += s2[(size_t)colsort[s + e] * F1 + jf];
    acc += __shfl_xor(acc, 16);
    acc += __shfl_xor(acc, 32);
    float z = dinv[i] * acc;

    bool act = lane < F2;
    int k = act ? lane : 0;
    float o = 0.f;
#pragma unroll
    for (int j = 0; j < F1; j++) {
        float zj = __shfl(z, j);
        o += zj * sW2[j * F2 + k];
    }
    float val = act ? o + b2[k] : -INFINITY;
    float m = val;
#pragma unroll
    for (int off = 1; off < 64; off <<= 1) m = fmaxf(m, __shfl_xor(m, off));
    float ex = act ? __expf(val - m) : 0.f;
    float ssum = ex;
#pragma unroll
    for (int off = 1; off < 64; off <<= 1) ssum += __shfl_xor(ssum, off);
    if (act) out[(size_t)i * F2 + lane] = val - m - __logf(ssum);
}

extern "C" void kernel_launch(void* const* d_in, const int* in_sizes, int n_in,
                              void* d_out, int out_size, void* d_ws, size_t ws_size,
                              hipStream_t stream) {
    const float* x  = (const float*)d_in[0];
    const float* W1 = (const float*)d_in[1];
    const float* b1 = (const float*)d_in[2];
    const float* W2 = (const float*)d_in[3];
    const float* b2 = (const float*)d_in[4];
    const int*   ei = (const int*)d_in[5];

    int n = in_sizes[0] / F0;
    int E = in_sizes[5] / 2;
    const int* row = ei;
    const int* col = ei + E;
    int NBC = (n + RPC - 1) >> RPC_SHIFT;        // coarse buckets
    int B1 = (E + EPB - 1) / EPB;                // partition blocks
    int NEL = NBC * B1;

    // workspace carve-up (4-byte elements)
    int* deg     = (int*)d_ws;            // n
    int* rs      = deg + n;               // n
    float* dinv  = (float*)(rs + n);      // n
    int* bh      = (int*)(dinv + n);      // NBC*B1
    int* cbstart = bh + NEL;              // NBC
    int* colsort = cbstart + NBC;         // E
    int* ebuf    = colsort + E;           // max(E, 32n) — overlaid with hp/s2
    float* hp    = (float*)ebuf;          // n x 16 (ebuf dead after k_bsort)
    float* s2    = hp + (size_t)n * F1;   // n x 16

    k_part_hist<<<B1, 256, 0, stream>>>(row, E, B1, NBC, bh);
    k_part_scan<<<1, 1024, 0, stream>>>(bh, NEL, B1, cbstart);
    k_part_fill<<<B1, 256, 0, stream>>>(row, col, E, B1, NBC, bh, ebuf);
    k_bsort<<<NBC, 256, 0, stream>>>(ebuf, cbstart, NBC, E, n, colsort, deg, rs, dinv);

    int g1_blocks = 2048;
    k_gemm1<<<g1_blocks, 256, 0, stream>>>(x, W1, dinv, hp, n, g1_blocks * 4);
    k_spmm1<<<(n + 3) / 4, 256, 0, stream>>>(hp, rs, deg, colsort, dinv, b1, s2, n);
    k_spmm2<<<(n + 3) / 4, 256, 0, stream>>>(s2, rs, deg, colsort, dinv, W2, b2,
                                             (float*)d_out, n);
}